// Round 2
// baseline (551.785 us; speedup 1.0000x reference)
//
#include <hip/hip_runtime.h>

// out[t, n*16+f] = relu(bias[f] + sum_{l=0}^{31} x[t-1-2l, n] * w_pn[l, f])
// w_pn = relu(w) / ||relu(w)||_2 (per filter column, over 32 lags)
//
// T=2048, N=4096 inputs, L=32 lags, F=16 filters, dilation=2.
// Tile: 64 t x 64 n per block (256 threads). Thread owns (n_local, f-quad),
// computes 4 same-parity t's at a time (share 31/35 staged x rows).
// Weights live in 128 VGPRs (w in LDS would make the LDS pipe the bottleneck).

constexpr int T = 2048;
constexpr int N = 4096;
constexpr int L = 32;
constexpr int F = 16;
constexpr int BT = 64;
constexpr int BN = 64;
constexpr int ROWS = BT + 62;          // 126 staged rows (t0-63 .. t0+62)
constexpr int OUT_STRIDE = N * F;      // 65536

typedef float vf4 __attribute__((ext_vector_type(4)));   // native vec for nontemporal store

__global__ __launch_bounds__(256, 2)
void tlayer_kernel(const float* __restrict__ x,
                   const float* __restrict__ w,
                   const float* __restrict__ bias,
                   float* __restrict__ out)
{
    __shared__ float sx[ROWS * BN];    // 32256 B
    __shared__ float sw[L * F];        // 2048 B
    __shared__ float sscale[F];

    const int tid = threadIdx.x;
    const int n0  = blockIdx.x * BN;
    const int t0  = blockIdx.y * BT;

    // ---- weight prep (redundant per block; 512 elements, trivial) ----
    sw[tid]       = fmaxf(w[tid], 0.f);
    sw[tid + 256] = fmaxf(w[tid + 256], 0.f);
    __syncthreads();
    if (tid < F) {
        float s = 0.f;
        #pragma unroll
        for (int l = 0; l < L; ++l) { float v = sw[l * F + tid]; s += v * v; }
        sscale[tid] = rsqrtf(fmaxf(s, 1e-12f));
    }
    __syncthreads();
    sw[tid]       *= sscale[tid & 15];
    sw[tid + 256] *= sscale[tid & 15];

    // ---- stage x tile: rows t0-63 .. t0+62, cols n0 .. n0+63, zero-padded ----
    for (int idx = tid; idx < ROWS * (BN / 4); idx += 256) {
        const int r  = idx >> 4;
        const int c4 = idx & 15;
        const int g  = t0 - 63 + r;
        float4 v = make_float4(0.f, 0.f, 0.f, 0.f);
        if (g >= 0 && g < T)
            v = *(const float4*)(x + (size_t)g * N + n0 + c4 * 4);
        *(float4*)(sx + r * BN + c4 * 4) = v;
    }
    __syncthreads();

    const int f4 = tid & 3;            // filter quad: f = 4*f4 .. 4*f4+3
    const int nl = tid >> 2;           // 0..63 local input unit
    const float4 b4 = *(const float4*)(bias + f4 * 4);

    // weights for my 4 filters -> registers (128 VGPRs)
    float4 wr[L];
    #pragma unroll
    for (int l = 0; l < L; ++l)
        wr[l] = *(const float4*)(sw + l * F + f4 * 4);

    float* outbase = out + (size_t)(n0 + nl) * F + f4 * 4;

    // 16 groups of 4 same-parity t's cover the 64-t tile
    for (int grp = 0; grp < 16; ++grp) {
        const int toff = (grp & 1) + (grp >> 1) * 8;   // tb - t0, tb = first t of group

        // rows needed: lds row (toff + 2m), m = 0..34
        float xv[35];
        const int base = toff * BN + nl;
        #pragma unroll
        for (int m = 0; m < 35; ++m)
            xv[m] = sx[base + m * (2 * BN)];

        float4 acc[4] = {b4, b4, b4, b4};
        #pragma unroll
        for (int l = 0; l < L; ++l) {
            const float4 w4 = wr[l];
            #pragma unroll
            for (int j = 0; j < 4; ++j) {
                const float xs = xv[31 + j - l];   // lag l for output t = tb + 2j
                acc[j].x = fmaf(xs, w4.x, acc[j].x);
                acc[j].y = fmaf(xs, w4.y, acc[j].y);
                acc[j].z = fmaf(xs, w4.z, acc[j].z);
                acc[j].w = fmaf(xs, w4.w, acc[j].w);
            }
        }

        #pragma unroll
        for (int j = 0; j < 4; ++j) {
            vf4 r;
            r.x = fmaxf(acc[j].x, 0.f);
            r.y = fmaxf(acc[j].y, 0.f);
            r.z = fmaxf(acc[j].z, 0.f);
            r.w = fmaxf(acc[j].w, 0.f);
            __builtin_nontemporal_store(
                r, (vf4*)(outbase + (size_t)(t0 + toff + 2 * j) * OUT_STRIDE));
        }
    }
}

extern "C" void kernel_launch(void* const* d_in, const int* in_sizes, int n_in,
                              void* d_out, int out_size, void* d_ws, size_t ws_size,
                              hipStream_t stream) {
    const float* x    = (const float*)d_in[0];   // [2048, 4096]
    const float* w    = (const float*)d_in[1];   // [32, 16]
    const float* bias = (const float*)d_in[2];   // [16]
    float* out = (float*)d_out;                  // [2048, 65536]

    dim3 grid(N / BN, T / BT);                   // (64, 32)
    tlayer_kernel<<<grid, 256, 0, stream>>>(x, w, bias, out);
}